// Round 2
// baseline (1432.641 us; speedup 1.0000x reference)
//
#include <hip/hip_runtime.h>

#define BB 256
#define NPER 512
#define FF 256
#define DD 32
#define EE 524288
#define NN (BB*NPER)          // 131072
#define NSTEPS 4

// ---------------- kernels ----------------

// degree (edges are constant across steps -> once per call)
__global__ void k_deg(const int* __restrict__ dst, float* __restrict__ degf) {
    int e = blockIdx.x * blockDim.x + threadIdx.x;
    atomicAdd(&degf[dst[e]], 1.0f);
}

// scatter: s[dst] += relu([xs,q][src] @ W_in + b_in); E x 8 threads, 4 channels each
__global__ void k_scatter(const int* __restrict__ src, const int* __restrict__ dst,
                          const float* __restrict__ xs, const float* __restrict__ q,
                          const float* __restrict__ Win, const float* __restrict__ bin,
                          float* __restrict__ s) {
    int t = blockIdx.x * blockDim.x + threadIdx.x;   // E*8 threads
    int e = t >> 3, g = t & 7;                       // channel group of 4
    int sv = src[e], dv = dst[e];
    float x = xs[sv], qq = q[sv];
    float4 wa = ((const float4*)Win)[g];             // Win[0, 4g..4g+3]
    float4 wb = ((const float4*)(Win + DD))[g];      // Win[1, 4g..4g+3]
    float4 bb = ((const float4*)bin)[g];
    float h0 = fmaxf(x * wa.x + qq * wb.x + bb.x, 0.f);
    float h1 = fmaxf(x * wa.y + qq * wb.y + bb.y, 0.f);
    float h2 = fmaxf(x * wa.z + qq * wb.z + bb.z, 0.f);
    float h3 = fmaxf(x * wa.w + qq * wb.w + bb.w, 0.f);
    float* sp = &s[dv * DD + g * 4];
    atomicAdd(sp + 0, h0);
    atomicAdd(sp + 1, h1);
    atomicAdd(sp + 2, h2);
    atomicAdd(sp + 3, h3);
}

// per node: agg = s_row@W_msg + deg*b_msg ; h2 = relu(h+agg); pred = h2@W_out + b_out
__global__ void k_node(const float* __restrict__ xs, const float* __restrict__ q,
                       const float* __restrict__ Win, const float* __restrict__ bin,
                       const float* __restrict__ s, const float* __restrict__ degf,
                       const float* __restrict__ Wmsg, const float* __restrict__ bmsg,
                       const float* __restrict__ Wout, const float* __restrict__ bout,
                       float* __restrict__ pred, float* __restrict__ out_preds, int step) {
    __shared__ float Wm[DD * DD];
    __shared__ float sl[8 * DD];
    int tid = threadIdx.x;                  // 256 = 8 nodes x 32 channels
    int i = blockIdx.x * 8 + (tid >> 5);
    int d = tid & 31;
    for (int k = tid; k < DD * DD; k += 256) Wm[k] = Wmsg[k];
    sl[tid] = s[i * DD + d];
    __syncthreads();
    float hval = fmaxf(xs[i] * Win[d] + q[i] * Win[DD + d] + bin[d], 0.f);
    float agg = degf[i] * bmsg[d];
    const float* srow = &sl[(tid >> 5) * DD];
    #pragma unroll
    for (int k = 0; k < DD; ++k) agg += srow[k] * Wm[k * DD + d];
    float h2 = fmaxf(hval + agg, 0.f);
    float v = h2 * Wout[d];
    for (int o = 16; o > 0; o >>= 1) v += __shfl_down(v, o, 32);
    if (d == 0) {
        float pr = v + bout[0];
        pred[i] = pr;
        out_preds[i * NSTEPS + step] = pr;
    }
}

// per graph (one block of 512): labels, normalized direction, init alphaMin
__global__ void k_graph(const float* __restrict__ xs, const float* __restrict__ xsol,
                        const float* __restrict__ pred,
                        float* __restrict__ out_labels, float* __restrict__ dd,
                        unsigned int* __restrict__ alphaMin, float tau, int step) {
    __shared__ float red[NPER];
    int b = blockIdx.x;
    int t = threadIdx.x;                 // 512
    int i = b * NPER + t;
    float x = xs[i];
    float r = xsol[i] - x;
    float p = pred[i];
    red[t] = fabsf(r);
    __syncthreads();
    for (int o = 256; o > 0; o >>= 1) { if (t < o) red[t] += red[t + o]; __syncthreads(); }
    float Sr = red[0] + 1e-12f;
    __syncthreads();
    red[t] = fabsf(p);
    __syncthreads();
    for (int o = 256; o > 0; o >>= 1) { if (t < o) red[t] += red[t + o]; __syncthreads(); }
    float Sp = red[0] + 1e-12f;
    out_labels[i * NSTEPS + step] = r / Sr;
    dd[i] = p / Sp + 3.0f * tau / (x + tau);
    if (t == 0) alphaMin[b] = 0x7f800000u;   // +inf bits (ratios are >= 0)
}

// dfp[b,sp,f] = sum_{n in split sp} P[b,n,f] * dd[b,n]
// block = 256 thr = 4 waves; wave w handles 32 rows; lane l = float4 column l
__global__ void k_df(const float* __restrict__ P, const float* __restrict__ dd,
                     float* __restrict__ dfp) {
    __shared__ float dl[128];
    __shared__ float sl[4 * FF];
    int b = blockIdx.x >> 2, sp = blockIdx.x & 3;
    int t = threadIdx.x, w = t >> 6, lane = t & 63;
    if (t < 128) dl[t] = dd[b * NPER + sp * 128 + t];
    __syncthreads();
    const float4* P4 = (const float4*)P + ((size_t)(b * NPER + sp * 128 + w * 32) * 64 + lane);
    float4 acc = {0.f, 0.f, 0.f, 0.f};
    const float* dw = &dl[w * 32];
    #pragma unroll 4
    for (int n = 0; n < 32; ++n) {
        float4 p = P4[(size_t)n * 64];
        float sc = dw[n];
        acc.x += p.x * sc; acc.y += p.y * sc; acc.z += p.z * sc; acc.w += p.w * sc;
    }
    ((float4*)sl)[w * 64 + lane] = acc;      // sl[w*256 + feature]
    __syncthreads();
    float v = sl[t] + sl[FF + t] + sl[2 * FF + t] + sl[3 * FF + t];
    dfp[((b << 2) + sp) * FF + t] = v;
}

// pproj[n] = P[b,n,:] . df[b,:]  (df = sum of 4 partials); line-search min per block
// block = 256 thr = 4 waves; wave covers 4 rows (1 float4/lane spans a full row)
__global__ void k_pproj(const float* __restrict__ P, const float* __restrict__ dfp,
                        const float* __restrict__ xs,
                        float* __restrict__ pproj, unsigned int* __restrict__ alphaMin) {
    __shared__ float mred[4];
    int t = threadIdx.x, w = t >> 6, lane = t & 63;
    int n0 = blockIdx.x * 16 + w * 4;
    int b = blockIdx.x >> 5;                  // 32 blocks per graph
    const float4* dp = (const float4*)dfp + (size_t)(b << 2) * 64 + lane;
    float4 d0 = dp[0], d1 = dp[64], d2 = dp[128], d3 = dp[192];
    float4 df4 = {d0.x + d1.x + d2.x + d3.x, d0.y + d1.y + d2.y + d3.y,
                  d0.z + d1.z + d2.z + d3.z, d0.w + d1.w + d2.w + d3.w};
    const float4* P4 = (const float4*)P + ((size_t)n0 * 64 + lane);
    float4 p0 = P4[0], p1 = P4[64], p2 = P4[128], p3 = P4[192];
    float a0 = p0.x * df4.x + p0.y * df4.y + p0.z * df4.z + p0.w * df4.w;
    float a1 = p1.x * df4.x + p1.y * df4.y + p1.z * df4.z + p1.w * df4.w;
    float a2 = p2.x * df4.x + p2.y * df4.y + p2.z * df4.z + p2.w * df4.w;
    float a3 = p3.x * df4.x + p3.y * df4.y + p3.z * df4.z + p3.w * df4.w;
    #pragma unroll
    for (int o = 32; o > 0; o >>= 1) {
        a0 += __shfl_down(a0, o, 64);
        a1 += __shfl_down(a1, o, 64);
        a2 += __shfl_down(a2, o, 64);
        a3 += __shfl_down(a3, o, 64);
    }
    if (lane == 0) {
        float acc[4] = {a0, a1, a2, a3};
        float m = 5.0f;
        #pragma unroll
        for (int k = 0; k < 4; ++k) {
            pproj[n0 + k] = acc[k];
            float x = xs[n0 + k];
            float ratio = (acc[k] < 0.f) ? (x / fmaxf(-acc[k], 1e-12f)) : 5.0f;
            m = fminf(m, ratio);
        }
        mred[w] = m;
    }
    __syncthreads();
    if (t == 0) {
        float m = fminf(fminf(mred[0], mred[1]), fminf(mred[2], mred[3]));
        atomicMin(&alphaMin[b], __float_as_uint(m));
    }
}

__global__ void k_update(const unsigned int* __restrict__ alphaMin,
                         const float* __restrict__ pproj, float* __restrict__ xs) {
    int i = blockIdx.x * blockDim.x + threadIdx.x;
    int b = i >> 9;
    float a = __uint_as_float(alphaMin[b]);
    a = fminf(fmaxf(a, 0.f), 5.0f) * 0.995f;
    xs[i] += a * pproj[i];
}

// ---------------- launch ----------------

extern "C" void kernel_launch(void* const* d_in, const int* in_sizes, int n_in,
                              void* d_out, int out_size, void* d_ws, size_t ws_size,
                              hipStream_t stream) {
    const float* x_start = (const float*)d_in[0];
    const float* x_sol   = (const float*)d_in[1];
    const float* q       = (const float*)d_in[2];
    const float* P       = (const float*)d_in[3];
    const float* Win     = (const float*)d_in[4];
    const float* bin     = (const float*)d_in[5];
    const float* Wmsg    = (const float*)d_in[6];
    const float* bmsg    = (const float*)d_in[7];
    const float* Wout    = (const float*)d_in[8];
    const float* bout    = (const float*)d_in[9];
    const int*   esrc    = (const int*)d_in[10];
    const int*   edst    = (const int*)d_in[11];
    // d_in[12] vals_batch unused: batch(i) == i >> 9 (equal-sized contiguous graphs)

    float* out_preds  = (float*)d_out;                // [N, 4] row-major
    float* out_labels = (float*)d_out + (size_t)NN * NSTEPS;

    float* w = (float*)d_ws;
    float* xs    = w; w += NN;
    float* s     = w; w += (size_t)NN * DD;
    float* degf  = w; w += NN;
    float* pred  = w; w += NN;
    float* ddv   = w; w += NN;
    float* pproj = w; w += NN;
    float* dfp   = w; w += (size_t)BB * 4 * FF;       // per-split df partials
    unsigned int* alphaMin = (unsigned int*)w; w += BB;

    hipMemcpyAsync(xs, x_start, NN * sizeof(float), hipMemcpyDeviceToDevice, stream);
    hipMemsetAsync(degf, 0, NN * sizeof(float), stream);
    k_deg<<<EE / 256, 256, 0, stream>>>(edst, degf);

    float tau = 0.1f;
    for (int step = 0; step < NSTEPS; ++step) {
        hipMemsetAsync(s, 0, (size_t)NN * DD * sizeof(float), stream);
        k_scatter<<<EE * 8 / 256, 256, 0, stream>>>(esrc, edst, xs, q, Win, bin, s);
        k_node<<<NN / 8, 256, 0, stream>>>(xs, q, Win, bin, s, degf, Wmsg, bmsg, Wout, bout,
                                           pred, out_preds, step);
        k_graph<<<BB, NPER, 0, stream>>>(xs, x_sol, pred, out_labels, ddv, alphaMin,
                                         tau, step);
        k_df<<<BB * 4, 256, 0, stream>>>(P, ddv, dfp);
        k_pproj<<<NN / 16, 256, 0, stream>>>(P, dfp, xs, pproj, alphaMin);
        k_update<<<NN / 256, 256, 0, stream>>>(alphaMin, pproj, xs);
        tau = fmaxf(tau * 0.5f, 1e-5f);
    }
}

// Round 3
// 666.114 us; speedup vs baseline: 2.1507x; 2.1507x over previous
//
#include <hip/hip_runtime.h>

#define BB 256
#define NPER 512
#define FF 256
#define DD 32
#define EE 524288
#define NN (BB*NPER)          // 131072
#define NSTEPS 4

// ---------------- CSR build (once per call; edges constant across steps) ----

__global__ void k_deg(const int* __restrict__ dst, unsigned* __restrict__ deg) {
    int e = blockIdx.x * blockDim.x + threadIdx.x;
    atomicAdd(&deg[dst[e]], 1u);
}

// per-256-block sums of deg
__global__ void k_bsum(const unsigned* __restrict__ deg, unsigned* __restrict__ bsum) {
    __shared__ unsigned r[256];
    int t = threadIdx.x;
    r[t] = deg[blockIdx.x * 256 + t];
    __syncthreads();
    for (int o = 128; o > 0; o >>= 1) { if (t < o) r[t] += r[t + o]; __syncthreads(); }
    if (t == 0) bsum[blockIdx.x] = r[0];
}

// exclusive scan of 512 block sums (single block)
__global__ void k_scanb(const unsigned* __restrict__ bsum, unsigned* __restrict__ bbase) {
    __shared__ unsigned r[512];
    int t = threadIdx.x;
    unsigned own = bsum[t];
    r[t] = own;
    __syncthreads();
    for (int o = 1; o < 512; o <<= 1) {
        unsigned v = (t >= o) ? r[t - o] : 0u;
        __syncthreads();
        r[t] += v;
        __syncthreads();
    }
    bbase[t] = r[t] - own;
}

// per-node exclusive offsets = block-local scan + bbase
__global__ void k_offsets(const unsigned* __restrict__ deg, const unsigned* __restrict__ bbase,
                          unsigned* __restrict__ rowstart, unsigned* __restrict__ cursor) {
    __shared__ unsigned r[256];
    int t = threadIdx.x;
    int i = blockIdx.x * 256 + t;
    unsigned d = deg[i];
    r[t] = d;
    __syncthreads();
    for (int o = 1; o < 256; o <<= 1) {
        unsigned v = (t >= o) ? r[t - o] : 0u;
        __syncthreads();
        r[t] += v;
        __syncthreads();
    }
    unsigned excl = r[t] - d + bbase[blockIdx.x];
    rowstart[i] = excl;
    cursor[i] = excl;
}

__global__ void k_fill(const int* __restrict__ src, const int* __restrict__ dst,
                       unsigned* __restrict__ cursor, int* __restrict__ csr_src) {
    int e = blockIdx.x * blockDim.x + threadIdx.x;
    unsigned pos = atomicAdd(&cursor[dst[e]], 1u);
    csr_src[pos] = src[e];
}

// ---------------- per-step kernels ----------------

// fused gather + node MLP: s = sum_{in-edges} relu(Win^T [xs,q][src] + bin);
// agg = s@Wmsg + deg*bmsg; h2 = relu(h+agg); pred = h2@Wout + bout
__global__ void k_node_g(const float* __restrict__ xs, const float* __restrict__ q,
                         const float* __restrict__ Win, const float* __restrict__ bin,
                         const unsigned* __restrict__ rowstart, const unsigned* __restrict__ deg,
                         const int* __restrict__ csr_src,
                         const float* __restrict__ Wmsg, const float* __restrict__ bmsg,
                         const float* __restrict__ Wout, const float* __restrict__ bout,
                         float* __restrict__ pred, float* __restrict__ out_preds, int step) {
    __shared__ float Wm[DD * DD];
    __shared__ float sl[8 * DD];
    int tid = threadIdx.x;                  // 256 = 8 nodes x 32 channels
    int ni = tid >> 5, d = tid & 31;
    int i = blockIdx.x * 8 + ni;
    for (int k = tid; k < DD * DD; k += 256) Wm[k] = Wmsg[k];
    float w0 = Win[d], w1 = Win[DD + d], b0 = bin[d];
    unsigned rs = rowstart[i];
    unsigned dg = deg[i];
    float s = 0.f;
    for (unsigned j = 0; j < dg; ++j) {
        int sv = csr_src[rs + j];           // broadcast within 32-lane group
        float hv = xs[sv] * w0 + q[sv] * w1 + b0;
        s += fmaxf(hv, 0.f);
    }
    sl[tid] = s;
    __syncthreads();
    float hval = fmaxf(xs[i] * w0 + q[i] * w1 + b0, 0.f);
    float agg = (float)dg * bmsg[d];
    const float* srow = &sl[ni * DD];
    #pragma unroll
    for (int k = 0; k < DD; ++k) agg += srow[k] * Wm[k * DD + d];
    float h2 = fmaxf(hval + agg, 0.f);
    float v = h2 * Wout[d];
    for (int o = 16; o > 0; o >>= 1) v += __shfl_down(v, o, 32);
    if (d == 0) {
        float pr = v + bout[0];
        pred[i] = pr;
        out_preds[i * NSTEPS + step] = pr;
    }
}

// per graph (one block of 512): labels, normalized direction, init alphaMin
__global__ void k_graph(const float* __restrict__ xs, const float* __restrict__ xsol,
                        const float* __restrict__ pred,
                        float* __restrict__ out_labels, float* __restrict__ dd,
                        unsigned int* __restrict__ alphaMin, float tau, int step) {
    __shared__ float red[NPER];
    int b = blockIdx.x;
    int t = threadIdx.x;                 // 512
    int i = b * NPER + t;
    float x = xs[i];
    float r = xsol[i] - x;
    float p = pred[i];
    red[t] = fabsf(r);
    __syncthreads();
    for (int o = 256; o > 0; o >>= 1) { if (t < o) red[t] += red[t + o]; __syncthreads(); }
    float Sr = red[0] + 1e-12f;
    __syncthreads();
    red[t] = fabsf(p);
    __syncthreads();
    for (int o = 256; o > 0; o >>= 1) { if (t < o) red[t] += red[t + o]; __syncthreads(); }
    float Sp = red[0] + 1e-12f;
    out_labels[i * NSTEPS + step] = r / Sr;
    dd[i] = p / Sp + 3.0f * tau / (x + tau);
    if (t == 0) alphaMin[b] = 0x7f800000u;   // +inf bits (ratios are >= 0)
}

// dfp[b,sp,f] = sum_{n in split sp} P[b,n,f] * dd[b,n]
__global__ void k_df(const float* __restrict__ P, const float* __restrict__ dd,
                     float* __restrict__ dfp) {
    __shared__ float dl[128];
    __shared__ float sl[4 * FF];
    int b = blockIdx.x >> 2, sp = blockIdx.x & 3;
    int t = threadIdx.x, w = t >> 6, lane = t & 63;
    if (t < 128) dl[t] = dd[b * NPER + sp * 128 + t];
    __syncthreads();
    const float4* P4 = (const float4*)P + ((size_t)(b * NPER + sp * 128 + w * 32) * 64 + lane);
    float4 acc = {0.f, 0.f, 0.f, 0.f};
    const float* dw = &dl[w * 32];
    #pragma unroll 4
    for (int n = 0; n < 32; ++n) {
        float4 p = P4[(size_t)n * 64];
        float sc = dw[n];
        acc.x += p.x * sc; acc.y += p.y * sc; acc.z += p.z * sc; acc.w += p.w * sc;
    }
    ((float4*)sl)[w * 64 + lane] = acc;      // sl[w*256 + feature]
    __syncthreads();
    float v = sl[t] + sl[FF + t] + sl[2 * FF + t] + sl[3 * FF + t];
    dfp[((b << 2) + sp) * FF + t] = v;
}

// pproj[n] = P[b,n,:] . df[b,:]; per-block line-search min -> atomicMin
__global__ void k_pproj(const float* __restrict__ P, const float* __restrict__ dfp,
                        const float* __restrict__ xs,
                        float* __restrict__ pproj, unsigned int* __restrict__ alphaMin) {
    __shared__ float mred[4];
    int t = threadIdx.x, w = t >> 6, lane = t & 63;
    int n0 = blockIdx.x * 16 + w * 4;
    int b = blockIdx.x >> 5;                  // 32 blocks per graph
    const float4* dp = (const float4*)dfp + (size_t)(b << 2) * 64 + lane;
    float4 d0 = dp[0], d1 = dp[64], d2 = dp[128], d3 = dp[192];
    float4 df4 = {d0.x + d1.x + d2.x + d3.x, d0.y + d1.y + d2.y + d3.y,
                  d0.z + d1.z + d2.z + d3.z, d0.w + d1.w + d2.w + d3.w};
    const float4* P4 = (const float4*)P + ((size_t)n0 * 64 + lane);
    float4 p0 = P4[0], p1 = P4[64], p2 = P4[128], p3 = P4[192];
    float a0 = p0.x * df4.x + p0.y * df4.y + p0.z * df4.z + p0.w * df4.w;
    float a1 = p1.x * df4.x + p1.y * df4.y + p1.z * df4.z + p1.w * df4.w;
    float a2 = p2.x * df4.x + p2.y * df4.y + p2.z * df4.z + p2.w * df4.w;
    float a3 = p3.x * df4.x + p3.y * df4.y + p3.z * df4.z + p3.w * df4.w;
    #pragma unroll
    for (int o = 32; o > 0; o >>= 1) {
        a0 += __shfl_down(a0, o, 64);
        a1 += __shfl_down(a1, o, 64);
        a2 += __shfl_down(a2, o, 64);
        a3 += __shfl_down(a3, o, 64);
    }
    if (lane == 0) {
        float acc[4] = {a0, a1, a2, a3};
        float m = 5.0f;
        #pragma unroll
        for (int k = 0; k < 4; ++k) {
            pproj[n0 + k] = acc[k];
            float x = xs[n0 + k];
            float ratio = (acc[k] < 0.f) ? (x / fmaxf(-acc[k], 1e-12f)) : 5.0f;
            m = fminf(m, ratio);
        }
        mred[w] = m;
    }
    __syncthreads();
    if (t == 0) {
        float m = fminf(fminf(mred[0], mred[1]), fminf(mred[2], mred[3]));
        atomicMin(&alphaMin[b], __float_as_uint(m));
    }
}

__global__ void k_update(const unsigned int* __restrict__ alphaMin,
                         const float* __restrict__ pproj, float* __restrict__ xs) {
    int i = blockIdx.x * blockDim.x + threadIdx.x;
    int b = i >> 9;
    float a = __uint_as_float(alphaMin[b]);
    a = fminf(fmaxf(a, 0.f), 5.0f) * 0.995f;
    xs[i] += a * pproj[i];
}

// ---------------- launch ----------------

extern "C" void kernel_launch(void* const* d_in, const int* in_sizes, int n_in,
                              void* d_out, int out_size, void* d_ws, size_t ws_size,
                              hipStream_t stream) {
    const float* x_start = (const float*)d_in[0];
    const float* x_sol   = (const float*)d_in[1];
    const float* q       = (const float*)d_in[2];
    const float* P       = (const float*)d_in[3];
    const float* Win     = (const float*)d_in[4];
    const float* bin     = (const float*)d_in[5];
    const float* Wmsg    = (const float*)d_in[6];
    const float* bmsg    = (const float*)d_in[7];
    const float* Wout    = (const float*)d_in[8];
    const float* bout    = (const float*)d_in[9];
    const int*   esrc    = (const int*)d_in[10];
    const int*   edst    = (const int*)d_in[11];
    // d_in[12] vals_batch unused: batch(i) == i >> 9 (equal-sized contiguous graphs)

    float* out_preds  = (float*)d_out;                // [N, 4] row-major
    float* out_labels = (float*)d_out + (size_t)NN * NSTEPS;

    float* w = (float*)d_ws;
    float* xs    = w; w += NN;
    float* pred  = w; w += NN;
    float* ddv   = w; w += NN;
    float* pproj = w; w += NN;
    float* dfp   = w; w += (size_t)BB * 4 * FF;       // per-split df partials
    unsigned* alphaMin = (unsigned*)w; w += BB;
    unsigned* deg      = (unsigned*)w; w += NN;
    unsigned* rowstart = (unsigned*)w; w += NN;
    unsigned* cursor   = (unsigned*)w; w += NN;
    unsigned* bsum     = (unsigned*)w; w += NN / 256;   // 512
    unsigned* bbase    = (unsigned*)w; w += NN / 256;   // 512
    int* csr_src       = (int*)w;      w += EE;

    // --- CSR build (edges constant across steps) ---
    hipMemsetAsync(deg, 0, NN * sizeof(unsigned), stream);
    k_deg<<<EE / 256, 256, 0, stream>>>(edst, deg);
    k_bsum<<<NN / 256, 256, 0, stream>>>(deg, bsum);
    k_scanb<<<1, NN / 256, 0, stream>>>(bsum, bbase);
    k_offsets<<<NN / 256, 256, 0, stream>>>(deg, bbase, rowstart, cursor);
    k_fill<<<EE / 256, 256, 0, stream>>>(esrc, edst, cursor, csr_src);

    hipMemcpyAsync(xs, x_start, NN * sizeof(float), hipMemcpyDeviceToDevice, stream);

    float tau = 0.1f;
    for (int step = 0; step < NSTEPS; ++step) {
        k_node_g<<<NN / 8, 256, 0, stream>>>(xs, q, Win, bin, rowstart, deg, csr_src,
                                             Wmsg, bmsg, Wout, bout, pred, out_preds, step);
        k_graph<<<BB, NPER, 0, stream>>>(xs, x_sol, pred, out_labels, ddv, alphaMin,
                                         tau, step);
        k_df<<<BB * 4, 256, 0, stream>>>(P, ddv, dfp);
        k_pproj<<<NN / 16, 256, 0, stream>>>(P, dfp, xs, pproj, alphaMin);
        k_update<<<NN / 256, 256, 0, stream>>>(alphaMin, pproj, xs);
        tau = fmaxf(tau * 0.5f, 1e-5f);
    }
}

// Round 4
// 548.336 us; speedup vs baseline: 2.6127x; 1.2148x over previous
//
#include <hip/hip_runtime.h>

#define BB 256
#define NPER 512
#define FF 256
#define DD 32
#define EE 524288
#define NN (BB*NPER)          // 131072
#define NSTEPS 4

__device__ __forceinline__ float bflo(unsigned u) { return __uint_as_float(u << 16); }
__device__ __forceinline__ float bfhi(unsigned u) { return __uint_as_float(u & 0xFFFF0000u); }

// ---------------- one-time kernels ----------------

__global__ void k_deg(const int* __restrict__ dst, unsigned* __restrict__ deg) {
    int e = blockIdx.x * blockDim.x + threadIdx.x;
    atomicAdd(&deg[dst[e]], 1u);
}

__global__ void k_bsum(const unsigned* __restrict__ deg, unsigned* __restrict__ bsum) {
    __shared__ unsigned r[256];
    int t = threadIdx.x;
    r[t] = deg[blockIdx.x * 256 + t];
    __syncthreads();
    for (int o = 128; o > 0; o >>= 1) { if (t < o) r[t] += r[t + o]; __syncthreads(); }
    if (t == 0) bsum[blockIdx.x] = r[0];
}

__global__ void k_scanb(const unsigned* __restrict__ bsum, unsigned* __restrict__ bbase) {
    __shared__ unsigned r[512];
    int t = threadIdx.x;
    unsigned own = bsum[t];
    r[t] = own;
    __syncthreads();
    for (int o = 1; o < 512; o <<= 1) {
        unsigned v = (t >= o) ? r[t - o] : 0u;
        __syncthreads();
        r[t] += v;
        __syncthreads();
    }
    bbase[t] = r[t] - own;
}

__global__ void k_offsets(const unsigned* __restrict__ deg, const unsigned* __restrict__ bbase,
                          unsigned* __restrict__ rowstart, unsigned* __restrict__ cursor) {
    __shared__ unsigned r[256];
    int t = threadIdx.x;
    int i = blockIdx.x * 256 + t;
    unsigned d = deg[i];
    r[t] = d;
    __syncthreads();
    for (int o = 1; o < 256; o <<= 1) {
        unsigned v = (t >= o) ? r[t - o] : 0u;
        __syncthreads();
        r[t] += v;
        __syncthreads();
    }
    unsigned excl = r[t] - d + bbase[blockIdx.x];
    rowstart[i] = excl;
    cursor[i] = excl;
}

__global__ void k_fill(const int* __restrict__ src, const int* __restrict__ dst,
                       unsigned* __restrict__ cursor, int* __restrict__ csr_src) {
    int e = blockIdx.x * blockDim.x + threadIdx.x;
    unsigned pos = atomicAdd(&cursor[dst[e]], 1u);
    csr_src[pos] = src[e];
}

// P fp32 -> bf16 (round-to-nearest), 4 elements/thread
__global__ void k_cast(const float* __restrict__ P, unsigned* __restrict__ Pbf2) {
    size_t i = (size_t)(blockIdx.x * blockDim.x + threadIdx.x);
    float4 p = ((const float4*)P)[i];
    unsigned u0 = __float_as_uint(p.x), u1 = __float_as_uint(p.y);
    unsigned u2 = __float_as_uint(p.z), u3 = __float_as_uint(p.w);
    u0 = (u0 + 0x7FFFu + ((u0 >> 16) & 1u)) >> 16;
    u1 = (u1 + 0x7FFFu + ((u1 >> 16) & 1u)) >> 16;
    u2 = (u2 + 0x7FFFu + ((u2 >> 16) & 1u)) >> 16;
    u3 = (u3 + 0x7FFFu + ((u3 >> 16) & 1u)) >> 16;
    uint2 o; o.x = u0 | (u1 << 16); o.y = u2 | (u3 << 16);
    ((uint2*)Pbf2)[i] = o;
}

// ---------------- per-step kernels ----------------

// fused gather + node MLP (parallel edge gather, shfl-broadcast compute)
__global__ void k_node_g(const float* __restrict__ xs, const float* __restrict__ q,
                         const float* __restrict__ Win, const float* __restrict__ bin,
                         const unsigned* __restrict__ rowstart, const unsigned* __restrict__ deg,
                         const int* __restrict__ csr_src,
                         const float* __restrict__ Wmsg, const float* __restrict__ bmsg,
                         const float* __restrict__ Wout, const float* __restrict__ bout,
                         float* __restrict__ pred, float* __restrict__ out_preds, int step) {
    __shared__ float Wm[DD * DD];
    __shared__ float sl[8 * DD];
    int tid = threadIdx.x;                  // 256 = 8 nodes x 32 channels
    int ni = tid >> 5, d = tid & 31;
    int i = blockIdx.x * 8 + ni;
    for (int k = tid; k < DD * DD; k += 256) Wm[k] = Wmsg[k];
    float w0 = Win[d], w1 = Win[DD + d], b0 = bin[d];
    unsigned rs = rowstart[i];
    unsigned dg = deg[i];
    unsigned nfull = dg < 32u ? dg : 32u;
    float xv = 0.f, qv = 0.f;
    if ((unsigned)d < nfull) {
        int sv = csr_src[rs + d];            // coalesced across lanes
        xv = xs[sv]; qv = q[sv];             // parallel independent gathers
    }
    float s = 0.f;
    for (unsigned j = 0; j < nfull; ++j) {
        float xj = __shfl(xv, (int)j, 32);
        float qj = __shfl(qv, (int)j, 32);
        s += fmaxf(xj * w0 + qj * w1 + b0, 0.f);
    }
    for (unsigned j = 32; j < dg; ++j) {     // rare tail (deg > 32)
        int sv = csr_src[rs + j];
        s += fmaxf(xs[sv] * w0 + q[sv] * w1 + b0, 0.f);
    }
    sl[tid] = s;
    __syncthreads();
    float hval = fmaxf(xs[i] * w0 + q[i] * w1 + b0, 0.f);
    float agg = (float)dg * bmsg[d];
    const float* srow = &sl[ni * DD];
    #pragma unroll
    for (int k = 0; k < DD; ++k) agg += srow[k] * Wm[k * DD + d];
    float h2 = fmaxf(hval + agg, 0.f);
    float v = h2 * Wout[d];
    for (int o = 16; o > 0; o >>= 1) v += __shfl_down(v, o, 32);
    if (d == 0) {
        float pr = v + bout[0];
        pred[i] = pr;
        out_preds[i * NSTEPS + step] = pr;
    }
}

// per graph: labels, normalized direction, init alphaMin (shuffle reductions)
__global__ void k_graph(const float* __restrict__ xs, const float* __restrict__ xsol,
                        const float* __restrict__ pred,
                        float* __restrict__ out_labels, float* __restrict__ dd,
                        unsigned int* __restrict__ alphaMin, float tau, int step) {
    __shared__ float s1[8], s2[8];
    int b = blockIdx.x;
    int t = threadIdx.x;                 // 512 = 8 waves
    int wid = t >> 6;
    int lane = t & 63;
    int i = b * NPER + t;
    float x = xs[i];
    float r = xsol[i] - x;
    float p = pred[i];
    float a1 = fabsf(r), a2 = fabsf(p);
    #pragma unroll
    for (int o = 32; o > 0; o >>= 1) {
        a1 += __shfl_down(a1, o, 64);
        a2 += __shfl_down(a2, o, 64);
    }
    if (lane == 0) { s1[wid] = a1; s2[wid] = a2; }
    __syncthreads();
    float Sr = 1e-12f, Sp = 1e-12f;
    #pragma unroll
    for (int k = 0; k < 8; ++k) { Sr += s1[k]; Sp += s2[k]; }
    out_labels[i * NSTEPS + step] = r / Sr;
    dd[i] = p / Sp + 3.0f * tau / (x + tau);
    if (t == 0) alphaMin[b] = 0x7f800000u;   // +inf bits (ratios are >= 0)
}

// dfp[b,sp,f] = sum_{n in split sp} P[b,n,f] * dd[b,n]   (P in bf16)
__global__ void k_df(const unsigned short* __restrict__ Pbf, const float* __restrict__ dd,
                     float* __restrict__ dfp) {
    __shared__ float dl[128];
    __shared__ float sl[4 * FF];
    int b = blockIdx.x >> 2, sp = blockIdx.x & 3;
    int t = threadIdx.x, w = t >> 6, lane = t & 63;
    if (t < 128) dl[t] = dd[b * NPER + sp * 128 + t];
    __syncthreads();
    const uint2* P2 = (const uint2*)(Pbf + (size_t)(b * NPER + sp * 128 + w * 32) * FF) + lane;
    float4 acc = {0.f, 0.f, 0.f, 0.f};
    const float* dw = &dl[w * 32];
    #pragma unroll 4
    for (int n = 0; n < 32; ++n) {
        uint2 pv = P2[(size_t)n * 64];
        float sc = dw[n];
        acc.x += bflo(pv.x) * sc; acc.y += bfhi(pv.x) * sc;
        acc.z += bflo(pv.y) * sc; acc.w += bfhi(pv.y) * sc;
    }
    ((float4*)sl)[w * 64 + lane] = acc;      // sl[w*256 + feature]
    __syncthreads();
    float v = sl[t] + sl[FF + t] + sl[2 * FF + t] + sl[3 * FF + t];
    dfp[((b << 2) + sp) * FF + t] = v;
}

// pproj[n] = P[b,n,:] . df[b,:]  (P in bf16); per-block line-search min
__global__ void k_pproj(const unsigned short* __restrict__ Pbf, const float* __restrict__ dfp,
                        const float* __restrict__ xs,
                        float* __restrict__ pproj, unsigned int* __restrict__ alphaMin) {
    __shared__ float mred[4];
    int t = threadIdx.x, w = t >> 6, lane = t & 63;
    int n0 = blockIdx.x * 16 + w * 4;
    int b = blockIdx.x >> 5;                  // 32 blocks per graph
    const float4* dp = (const float4*)dfp + (size_t)(b << 2) * 64 + lane;
    float4 d0 = dp[0], d1 = dp[64], d2 = dp[128], d3 = dp[192];
    float4 df4 = {d0.x + d1.x + d2.x + d3.x, d0.y + d1.y + d2.y + d3.y,
                  d0.z + d1.z + d2.z + d3.z, d0.w + d1.w + d2.w + d3.w};
    const uint2* P2 = (const uint2*)(Pbf + (size_t)n0 * FF) + lane;
    uint2 p0 = P2[0], p1 = P2[64], p2 = P2[128], p3 = P2[192];
    float a0 = bflo(p0.x) * df4.x + bfhi(p0.x) * df4.y + bflo(p0.y) * df4.z + bfhi(p0.y) * df4.w;
    float a1 = bflo(p1.x) * df4.x + bfhi(p1.x) * df4.y + bflo(p1.y) * df4.z + bfhi(p1.y) * df4.w;
    float a2 = bflo(p2.x) * df4.x + bfhi(p2.x) * df4.y + bflo(p2.y) * df4.z + bfhi(p2.y) * df4.w;
    float a3 = bflo(p3.x) * df4.x + bfhi(p3.x) * df4.y + bflo(p3.y) * df4.z + bfhi(p3.y) * df4.w;
    #pragma unroll
    for (int o = 32; o > 0; o >>= 1) {
        a0 += __shfl_down(a0, o, 64);
        a1 += __shfl_down(a1, o, 64);
        a2 += __shfl_down(a2, o, 64);
        a3 += __shfl_down(a3, o, 64);
    }
    if (lane == 0) {
        float acc[4] = {a0, a1, a2, a3};
        float m = 5.0f;
        #pragma unroll
        for (int k = 0; k < 4; ++k) {
            pproj[n0 + k] = acc[k];
            float x = xs[n0 + k];
            float ratio = (acc[k] < 0.f) ? (x / fmaxf(-acc[k], 1e-12f)) : 5.0f;
            m = fminf(m, ratio);
        }
        mred[w] = m;
    }
    __syncthreads();
    if (t == 0) {
        float m = fminf(fminf(mred[0], mred[1]), fminf(mred[2], mred[3]));
        atomicMin(&alphaMin[b], __float_as_uint(m));
    }
}

__global__ void k_update(const unsigned int* __restrict__ alphaMin,
                         const float* __restrict__ pproj, float* __restrict__ xs) {
    int i = blockIdx.x * blockDim.x + threadIdx.x;
    int b = i >> 9;
    float a = __uint_as_float(alphaMin[b]);
    a = fminf(fmaxf(a, 0.f), 5.0f) * 0.995f;
    xs[i] += a * pproj[i];
}

// ---------------- launch ----------------

extern "C" void kernel_launch(void* const* d_in, const int* in_sizes, int n_in,
                              void* d_out, int out_size, void* d_ws, size_t ws_size,
                              hipStream_t stream) {
    const float* x_start = (const float*)d_in[0];
    const float* x_sol   = (const float*)d_in[1];
    const float* q       = (const float*)d_in[2];
    const float* P       = (const float*)d_in[3];
    const float* Win     = (const float*)d_in[4];
    const float* bin     = (const float*)d_in[5];
    const float* Wmsg    = (const float*)d_in[6];
    const float* bmsg    = (const float*)d_in[7];
    const float* Wout    = (const float*)d_in[8];
    const float* bout    = (const float*)d_in[9];
    const int*   esrc    = (const int*)d_in[10];
    const int*   edst    = (const int*)d_in[11];
    // d_in[12] vals_batch unused: batch(i) == i >> 9 (equal-sized contiguous graphs)

    float* out_preds  = (float*)d_out;                // [N, 4] row-major
    float* out_labels = (float*)d_out + (size_t)NN * NSTEPS;

    float* w = (float*)d_ws;
    float* xs    = w; w += NN;
    float* pred  = w; w += NN;
    float* ddv   = w; w += NN;
    float* pproj = w; w += NN;
    float* dfp   = w; w += (size_t)BB * 4 * FF;       // per-split df partials
    unsigned* alphaMin = (unsigned*)w; w += BB;
    unsigned* deg      = (unsigned*)w; w += NN;
    unsigned* rowstart = (unsigned*)w; w += NN;
    unsigned* cursor   = (unsigned*)w; w += NN;
    unsigned* bsum     = (unsigned*)w; w += NN / 256;   // 512
    unsigned* bbase    = (unsigned*)w; w += NN / 256;   // 512
    int* csr_src       = (int*)w;      w += EE;
    unsigned short* Pbf = (unsigned short*)w;           // 64 MB bf16 copy of P

    // --- one-time: CSR build + P cast ---
    hipMemsetAsync(deg, 0, NN * sizeof(unsigned), stream);
    k_deg<<<EE / 256, 256, 0, stream>>>(edst, deg);
    k_cast<<<(BB * NPER * FF / 4) / 256, 256, 0, stream>>>(P, (unsigned*)Pbf);
    k_bsum<<<NN / 256, 256, 0, stream>>>(deg, bsum);
    k_scanb<<<1, NN / 256, 0, stream>>>(bsum, bbase);
    k_offsets<<<NN / 256, 256, 0, stream>>>(deg, bbase, rowstart, cursor);
    k_fill<<<EE / 256, 256, 0, stream>>>(esrc, edst, cursor, csr_src);

    hipMemcpyAsync(xs, x_start, NN * sizeof(float), hipMemcpyDeviceToDevice, stream);

    float tau = 0.1f;
    for (int step = 0; step < NSTEPS; ++step) {
        k_node_g<<<NN / 8, 256, 0, stream>>>(xs, q, Win, bin, rowstart, deg, csr_src,
                                             Wmsg, bmsg, Wout, bout, pred, out_preds, step);
        k_graph<<<BB, NPER, 0, stream>>>(xs, x_sol, pred, out_labels, ddv, alphaMin,
                                         tau, step);
        if (step < NSTEPS - 1) {   // step-4 projection/update is dead work
            k_df<<<BB * 4, 256, 0, stream>>>(Pbf, ddv, dfp);
            k_pproj<<<NN / 16, 256, 0, stream>>>(Pbf, dfp, xs, pproj, alphaMin);
            k_update<<<NN / 256, 256, 0, stream>>>(alphaMin, pproj, xs);
        }
        tau = fmaxf(tau * 0.5f, 1e-5f);
    }
}

// Round 5
// 525.260 us; speedup vs baseline: 2.7275x; 1.0439x over previous
//
#include <hip/hip_runtime.h>

#define BB 256
#define NPER 512
#define FF 256
#define DD 32
#define EE 524288
#define NN (BB*NPER)          // 131072
#define NSTEPS 4

__device__ __forceinline__ float bflo(unsigned u) { return __uint_as_float(u << 16); }
__device__ __forceinline__ float bfhi(unsigned u) { return __uint_as_float(u & 0xFFFF0000u); }

// ---------------- one-time kernels ----------------

__global__ void k_deg(const int* __restrict__ dst, unsigned* __restrict__ deg) {
    int e = blockIdx.x * blockDim.x + threadIdx.x;
    atomicAdd(&deg[dst[e]], 1u);
}

__global__ void k_bsum(const unsigned* __restrict__ deg, unsigned* __restrict__ bsum) {
    __shared__ unsigned r[256];
    int t = threadIdx.x;
    r[t] = deg[blockIdx.x * 256 + t];
    __syncthreads();
    for (int o = 128; o > 0; o >>= 1) { if (t < o) r[t] += r[t + o]; __syncthreads(); }
    if (t == 0) bsum[blockIdx.x] = r[0];
}

__global__ void k_scanb(const unsigned* __restrict__ bsum, unsigned* __restrict__ bbase) {
    __shared__ unsigned r[512];
    int t = threadIdx.x;
    unsigned own = bsum[t];
    r[t] = own;
    __syncthreads();
    for (int o = 1; o < 512; o <<= 1) {
        unsigned v = (t >= o) ? r[t - o] : 0u;
        __syncthreads();
        r[t] += v;
        __syncthreads();
    }
    bbase[t] = r[t] - own;
}

__global__ void k_offsets(const unsigned* __restrict__ deg, const unsigned* __restrict__ bbase,
                          unsigned* __restrict__ rowstart, unsigned* __restrict__ cursor) {
    __shared__ unsigned r[256];
    int t = threadIdx.x;
    int i = blockIdx.x * 256 + t;
    unsigned d = deg[i];
    r[t] = d;
    __syncthreads();
    for (int o = 1; o < 256; o <<= 1) {
        unsigned v = (t >= o) ? r[t - o] : 0u;
        __syncthreads();
        r[t] += v;
        __syncthreads();
    }
    unsigned excl = r[t] - d + bbase[blockIdx.x];
    rowstart[i] = excl;
    cursor[i] = excl;
}

__global__ void k_fill(const int* __restrict__ src, const int* __restrict__ dst,
                       unsigned* __restrict__ cursor, int* __restrict__ csr_src) {
    int e = blockIdx.x * blockDim.x + threadIdx.x;
    unsigned pos = atomicAdd(&cursor[dst[e]], 1u);
    csr_src[pos] = src[e];
}

// P fp32 -> bf16 (round-to-nearest)
__global__ void k_cast(const float* __restrict__ P, unsigned* __restrict__ Pbf2) {
    size_t i = (size_t)(blockIdx.x * blockDim.x + threadIdx.x);
    float4 p = ((const float4*)P)[i];
    unsigned u0 = __float_as_uint(p.x), u1 = __float_as_uint(p.y);
    unsigned u2 = __float_as_uint(p.z), u3 = __float_as_uint(p.w);
    u0 = (u0 + 0x7FFFu + ((u0 >> 16) & 1u)) >> 16;
    u1 = (u1 + 0x7FFFu + ((u1 >> 16) & 1u)) >> 16;
    u2 = (u2 + 0x7FFFu + ((u2 >> 16) & 1u)) >> 16;
    u3 = (u3 + 0x7FFFu + ((u3 >> 16) & 1u)) >> 16;
    uint2 o; o.x = u0 | (u1 << 16); o.y = u2 | (u3 << 16);
    ((uint2*)Pbf2)[i] = o;
}

__global__ void k_pack(const float* __restrict__ xs0, const float* __restrict__ q,
                       float2* __restrict__ xq) {
    int i = blockIdx.x * blockDim.x + threadIdx.x;
    float2 v; v.x = xs0[i]; v.y = q[i];
    xq[i] = v;
}

// ---------------- per-step kernels ----------------

// fused gather + node MLP; Wmsg column in VGPRs, s broadcast via shfl (no LDS)
__global__ void k_node_g(const float2* __restrict__ xq,
                         const float* __restrict__ Win, const float* __restrict__ bin,
                         const unsigned* __restrict__ rowstart, const unsigned* __restrict__ deg,
                         const int* __restrict__ csr_src,
                         const float* __restrict__ Wmsg, const float* __restrict__ bmsg,
                         const float* __restrict__ Wout, const float* __restrict__ bout,
                         float* __restrict__ pred, float* __restrict__ out_preds, int step) {
    int tid = threadIdx.x;                  // 256 = 8 nodes x 32 channels
    int d = tid & 31;
    int i = blockIdx.x * 8 + (tid >> 5);
    float w0 = Win[d], w1 = Win[DD + d], b0 = bin[d];
    float wcol[DD];
    #pragma unroll
    for (int k = 0; k < DD; ++k) wcol[k] = Wmsg[k * DD + d];   // coalesced, L1-cached
    unsigned rs = rowstart[i];
    unsigned dg = deg[i];
    unsigned nfull = dg < 32u ? dg : 32u;
    float xv = 0.f, qv = 0.f;
    if ((unsigned)d < nfull) {
        int sv = csr_src[rs + d];            // coalesced across lanes
        float2 v = xq[sv];                   // single 8B gather per edge
        xv = v.x; qv = v.y;
    }
    float s = 0.f;
    for (unsigned j = 0; j < nfull; ++j) {
        float xj = __shfl(xv, (int)j, 32);
        float qj = __shfl(qv, (int)j, 32);
        s += fmaxf(xj * w0 + qj * w1 + b0, 0.f);
    }
    for (unsigned j = 32; j < dg; ++j) {     // rare tail (deg > 32)
        int sv = csr_src[rs + j];
        float2 v = xq[sv];
        s += fmaxf(v.x * w0 + v.y * w1 + b0, 0.f);
    }
    float2 self = xq[i];
    float hval = fmaxf(self.x * w0 + self.y * w1 + b0, 0.f);
    float agg = (float)dg * bmsg[d];
    #pragma unroll
    for (int k = 0; k < DD; ++k) agg += __shfl(s, k, 32) * wcol[k];
    float h2 = fmaxf(hval + agg, 0.f);
    float v = h2 * Wout[d];
    for (int o = 16; o > 0; o >>= 1) v += __shfl_down(v, o, 32);
    if (d == 0) {
        float pr = v + bout[0];
        pred[i] = pr;
        out_preds[i * NSTEPS + step] = pr;
    }
}

// per graph: labels, normalized direction, zero df, init alphaMin
__global__ void k_graph(const float2* __restrict__ xq, const float* __restrict__ xsol,
                        const float* __restrict__ pred,
                        float* __restrict__ out_labels, float* __restrict__ dd,
                        float* __restrict__ df,
                        unsigned int* __restrict__ alphaMin, float tau, int step) {
    __shared__ float s1[8], s2[8];
    int b = blockIdx.x;
    int t = threadIdx.x;                 // 512 = 8 waves
    int wid = t >> 6;
    int lane = t & 63;
    int i = b * NPER + t;
    float x = xq[i].x;
    float r = xsol[i] - x;
    float p = pred[i];
    float a1 = fabsf(r), a2 = fabsf(p);
    #pragma unroll
    for (int o = 32; o > 0; o >>= 1) {
        a1 += __shfl_down(a1, o, 64);
        a2 += __shfl_down(a2, o, 64);
    }
    if (lane == 0) { s1[wid] = a1; s2[wid] = a2; }
    __syncthreads();
    float Sr = 1e-12f, Sp = 1e-12f;
    #pragma unroll
    for (int k = 0; k < 8; ++k) { Sr += s1[k]; Sp += s2[k]; }
    out_labels[i * NSTEPS + step] = r / Sr;
    dd[i] = p / Sp + 3.0f * tau / (x + tau);
    if (t < FF) df[b * FF + t] = 0.f;
    if (t == 0) alphaMin[b] = 0x7f800000u;   // +inf bits (ratios are >= 0)
}

// df[b,f] += sum_{n in split sp} P[b,n,f] * dd[b,n]   (P bf16, atomic fold)
__global__ void k_df(const unsigned short* __restrict__ Pbf, const float* __restrict__ dd,
                     float* __restrict__ df) {
    __shared__ float dl[128];
    __shared__ float sl[4 * FF];
    int b = blockIdx.x >> 2, sp = blockIdx.x & 3;
    int t = threadIdx.x, w = t >> 6, lane = t & 63;
    if (t < 128) dl[t] = dd[b * NPER + sp * 128 + t];
    __syncthreads();
    const uint2* P2 = (const uint2*)(Pbf + (size_t)(b * NPER + sp * 128 + w * 32) * FF) + lane;
    float4 acc = {0.f, 0.f, 0.f, 0.f};
    const float* dw = &dl[w * 32];
    #pragma unroll 4
    for (int n = 0; n < 32; ++n) {
        uint2 pv = P2[(size_t)n * 64];
        float sc = dw[n];
        acc.x += bflo(pv.x) * sc; acc.y += bfhi(pv.x) * sc;
        acc.z += bflo(pv.y) * sc; acc.w += bfhi(pv.y) * sc;
    }
    ((float4*)sl)[w * 64 + lane] = acc;      // sl[w*256 + feature]
    __syncthreads();
    float v = sl[t] + sl[FF + t] + sl[2 * FF + t] + sl[3 * FF + t];
    atomicAdd(&df[b * FF + t], v);           // 4 contributions per element, L2-resident
}

// pproj[n] = P[b,n,:] . df[b,:]  (uint4 loads, 32-lane row halves); line-search min
__global__ void k_pproj(const unsigned short* __restrict__ Pbf, const float* __restrict__ df,
                        const float2* __restrict__ xq,
                        float* __restrict__ pproj, unsigned int* __restrict__ alphaMin) {
    __shared__ float mred[4];
    int t = threadIdx.x, w = t >> 6, lane = t & 63;
    int hl = lane >> 5, l5 = lane & 31;
    int b = blockIdx.x >> 4;                  // 16 blocks per graph, 32 rows per block
    const float4* dfp4 = (const float4*)(df + (size_t)b * FF);
    float4 dfa = dfp4[l5 * 2], dfb = dfp4[l5 * 2 + 1];   // features l5*8 .. l5*8+7
    int n0 = blockIdx.x * 32 + w * 8 + hl;
    float m = 5.0f;
    #pragma unroll
    for (int it = 0; it < 4; ++it) {
        int n = n0 + it * 2;
        uint4 pv = ((const uint4*)(Pbf + (size_t)n * FF))[l5];
        float acc = bflo(pv.x) * dfa.x + bfhi(pv.x) * dfa.y
                  + bflo(pv.y) * dfa.z + bfhi(pv.y) * dfa.w
                  + bflo(pv.z) * dfb.x + bfhi(pv.z) * dfb.y
                  + bflo(pv.w) * dfb.z + bfhi(pv.w) * dfb.w;
        #pragma unroll
        for (int o = 16; o > 0; o >>= 1) acc += __shfl_down(acc, o, 32);
        if (l5 == 0) {
            pproj[n] = acc;
            float x = xq[n].x;
            float ratio = (acc < 0.f) ? (x / fmaxf(-acc, 1e-12f)) : 5.0f;
            m = fminf(m, ratio);
        }
    }
    m = fminf(m, __shfl_xor(m, 32, 64));     // combine the two 32-lane halves
    if (lane == 0) mred[w] = m;
    __syncthreads();
    if (t == 0) {
        float mm = fminf(fminf(mred[0], mred[1]), fminf(mred[2], mred[3]));
        atomicMin(&alphaMin[b], __float_as_uint(mm));
    }
}

__global__ void k_update(const unsigned int* __restrict__ alphaMin,
                         const float* __restrict__ pproj, float2* __restrict__ xq) {
    int i = blockIdx.x * blockDim.x + threadIdx.x;
    int b = i >> 9;
    float a = __uint_as_float(alphaMin[b]);
    a = fminf(fmaxf(a, 0.f), 5.0f) * 0.995f;
    xq[i].x += a * pproj[i];
}

// ---------------- launch ----------------

extern "C" void kernel_launch(void* const* d_in, const int* in_sizes, int n_in,
                              void* d_out, int out_size, void* d_ws, size_t ws_size,
                              hipStream_t stream) {
    const float* x_start = (const float*)d_in[0];
    const float* x_sol   = (const float*)d_in[1];
    const float* q       = (const float*)d_in[2];
    const float* P       = (const float*)d_in[3];
    const float* Win     = (const float*)d_in[4];
    const float* bin     = (const float*)d_in[5];
    const float* Wmsg    = (const float*)d_in[6];
    const float* bmsg    = (const float*)d_in[7];
    const float* Wout    = (const float*)d_in[8];
    const float* bout    = (const float*)d_in[9];
    const int*   esrc    = (const int*)d_in[10];
    const int*   edst    = (const int*)d_in[11];
    // d_in[12] vals_batch unused: batch(i) == i >> 9 (equal-sized contiguous graphs)

    float* out_preds  = (float*)d_out;                // [N, 4] row-major
    float* out_labels = (float*)d_out + (size_t)NN * NSTEPS;

    float* w = (float*)d_ws;
    float2* xq  = (float2*)w; w += 2 * (size_t)NN;
    float* pred  = w; w += NN;
    float* ddv   = w; w += NN;
    float* pproj = w; w += NN;
    float* df    = w; w += (size_t)BB * FF;
    unsigned* alphaMin = (unsigned*)w; w += BB;
    unsigned* deg      = (unsigned*)w; w += NN;
    unsigned* rowstart = (unsigned*)w; w += NN;
    unsigned* cursor   = (unsigned*)w; w += NN;
    unsigned* bsum     = (unsigned*)w; w += NN / 256;   // 512
    unsigned* bbase    = (unsigned*)w; w += NN / 256;   // 512
    int* csr_src       = (int*)w;      w += EE;
    unsigned short* Pbf = (unsigned short*)w;           // 64 MB bf16 copy of P

    // --- one-time: CSR build + P cast + xq pack ---
    hipMemsetAsync(deg, 0, NN * sizeof(unsigned), stream);
    k_deg<<<EE / 256, 256, 0, stream>>>(edst, deg);
    k_cast<<<(BB * NPER * FF / 4) / 256, 256, 0, stream>>>(P, (unsigned*)Pbf);
    k_pack<<<NN / 256, 256, 0, stream>>>(x_start, q, xq);
    k_bsum<<<NN / 256, 256, 0, stream>>>(deg, bsum);
    k_scanb<<<1, NN / 256, 0, stream>>>(bsum, bbase);
    k_offsets<<<NN / 256, 256, 0, stream>>>(deg, bbase, rowstart, cursor);
    k_fill<<<EE / 256, 256, 0, stream>>>(esrc, edst, cursor, csr_src);

    float tau = 0.1f;
    for (int step = 0; step < NSTEPS; ++step) {
        k_node_g<<<NN / 8, 256, 0, stream>>>(xq, Win, bin, rowstart, deg, csr_src,
                                             Wmsg, bmsg, Wout, bout, pred, out_preds, step);
        k_graph<<<BB, NPER, 0, stream>>>(xq, x_sol, pred, out_labels, ddv, df, alphaMin,
                                         tau, step);
        if (step < NSTEPS - 1) {   // step-4 projection/update is dead work
            k_df<<<BB * 4, 256, 0, stream>>>(Pbf, ddv, df);
            k_pproj<<<NN / 32, 256, 0, stream>>>(Pbf, df, xq, pproj, alphaMin);
            k_update<<<NN / 256, 256, 0, stream>>>(alphaMin, pproj, xq);
        }
        tau = fmaxf(tau * 0.5f, 1e-5f);
    }
}

// Round 6
// 514.223 us; speedup vs baseline: 2.7860x; 1.0215x over previous
//
#include <hip/hip_runtime.h>

#define BB 256
#define NPER 512
#define FF 256
#define DD 32
#define EE 524288
#define NN (BB*NPER)          // 131072
#define NSTEPS 4

__device__ __forceinline__ float bflo(unsigned u) { return __uint_as_float(u << 16); }
__device__ __forceinline__ float bfhi(unsigned u) { return __uint_as_float(u & 0xFFFF0000u); }
__device__ __forceinline__ unsigned rtn_bf16(unsigned u) {
    return (u + 0x7FFFu + ((u >> 16) & 1u)) >> 16;
}

// ---------------- one-time kernels ----------------

// deg histogram + xq pack fused (EE threads; first NN do the pack)
__global__ void k_degpack(const int* __restrict__ dst, unsigned* __restrict__ deg,
                          const float* __restrict__ xs0, const float* __restrict__ q,
                          float2* __restrict__ xq) {
    int t = blockIdx.x * blockDim.x + threadIdx.x;
    if (t < NN) { float2 v; v.x = xs0[t]; v.y = q[t]; xq[t] = v; }
    atomicAdd(&deg[dst[t]], 1u);
}

__global__ void k_bsum(const unsigned* __restrict__ deg, unsigned* __restrict__ bsum) {
    __shared__ unsigned r[256];
    int t = threadIdx.x;
    r[t] = deg[blockIdx.x * 256 + t];
    __syncthreads();
    for (int o = 128; o > 0; o >>= 1) { if (t < o) r[t] += r[t + o]; __syncthreads(); }
    if (t == 0) bsum[blockIdx.x] = r[0];
}

__global__ void k_scanb(const unsigned* __restrict__ bsum, unsigned* __restrict__ bbase) {
    __shared__ unsigned r[512];
    int t = threadIdx.x;
    unsigned own = bsum[t];
    r[t] = own;
    __syncthreads();
    for (int o = 1; o < 512; o <<= 1) {
        unsigned v = (t >= o) ? r[t - o] : 0u;
        __syncthreads();
        r[t] += v;
        __syncthreads();
    }
    bbase[t] = r[t] - own;
}

__global__ void k_offsets(const unsigned* __restrict__ deg, const unsigned* __restrict__ bbase,
                          unsigned* __restrict__ rowstart, unsigned* __restrict__ cursor) {
    __shared__ unsigned r[256];
    int t = threadIdx.x;
    int i = blockIdx.x * 256 + t;
    unsigned d = deg[i];
    r[t] = d;
    __syncthreads();
    for (int o = 1; o < 256; o <<= 1) {
        unsigned v = (t >= o) ? r[t - o] : 0u;
        __syncthreads();
        r[t] += v;
        __syncthreads();
    }
    unsigned excl = r[t] - d + bbase[blockIdx.x];
    rowstart[i] = excl;
    cursor[i] = excl;
}

__global__ void k_fill(const int* __restrict__ src, const int* __restrict__ dst,
                       unsigned* __restrict__ cursor, int* __restrict__ csr_src) {
    int e = blockIdx.x * blockDim.x + threadIdx.x;
    unsigned pos = atomicAdd(&cursor[dst[e]], 1u);
    csr_src[pos] = src[e];
}

// ---------------- per-step kernels ----------------

// fused gather + node MLP; Wmsg column in VGPRs, s broadcast via shfl (no LDS)
__global__ void k_node_g(const float2* __restrict__ xq,
                         const float* __restrict__ Win, const float* __restrict__ bin,
                         const unsigned* __restrict__ rowstart, const unsigned* __restrict__ deg,
                         const int* __restrict__ csr_src,
                         const float* __restrict__ Wmsg, const float* __restrict__ bmsg,
                         const float* __restrict__ Wout, const float* __restrict__ bout,
                         float* __restrict__ pred, float* __restrict__ out_preds, int step) {
    int tid = threadIdx.x;                  // 256 = 8 nodes x 32 channels
    int d = tid & 31;
    int i = blockIdx.x * 8 + (tid >> 5);
    float w0 = Win[d], w1 = Win[DD + d], b0 = bin[d];
    float wcol[DD];
    #pragma unroll
    for (int k = 0; k < DD; ++k) wcol[k] = Wmsg[k * DD + d];   // coalesced, L1-cached
    unsigned rs = rowstart[i];
    unsigned dg = deg[i];
    unsigned nfull = dg < 32u ? dg : 32u;
    float xv = 0.f, qv = 0.f;
    if ((unsigned)d < nfull) {
        int sv = csr_src[rs + d];            // coalesced across lanes
        float2 v = xq[sv];                   // single 8B gather per edge
        xv = v.x; qv = v.y;
    }
    float s = 0.f;
    for (unsigned j = 0; j < nfull; ++j) {
        float xj = __shfl(xv, (int)j, 32);
        float qj = __shfl(qv, (int)j, 32);
        s += fmaxf(xj * w0 + qj * w1 + b0, 0.f);
    }
    for (unsigned j = 32; j < dg; ++j) {     // rare tail (deg > 32)
        int sv = csr_src[rs + j];
        float2 v = xq[sv];
        s += fmaxf(v.x * w0 + v.y * w1 + b0, 0.f);
    }
    float2 self = xq[i];
    float hval = fmaxf(self.x * w0 + self.y * w1 + b0, 0.f);
    float agg = (float)dg * bmsg[d];
    #pragma unroll
    for (int k = 0; k < DD; ++k) agg += __shfl(s, k, 32) * wcol[k];
    float h2 = fmaxf(hval + agg, 0.f);
    float v = h2 * Wout[d];
    for (int o = 16; o > 0; o >>= 1) v += __shfl_down(v, o, 32);
    if (d == 0) {
        float pr = v + bout[0];
        pred[i] = pr;
        out_preds[i * NSTEPS + step] = pr;
    }
}

// mega per-graph kernel: labels + direction + df + pproj + line search + update.
// One block (512 thr) per graph. Step 0 reads fp32 P and writes the bf16 copy
// inline; later steps read bf16 (L3-resident). Last step: labels only.
__global__ __launch_bounds__(512) void k_step(const float* __restrict__ Pf,
                                              unsigned short* __restrict__ Pbf,
                                              float2* __restrict__ xq,
                                              const float* __restrict__ xsol,
                                              const float* __restrict__ pred,
                                              float* __restrict__ out_labels,
                                              float tau, int step) {
    __shared__ float ddl[NPER];
    __shared__ float sl[8 * FF];
    __shared__ float dfl[FF];
    __shared__ float pp[NPER];
    __shared__ float red[8], red2[8];
    int b = blockIdx.x;
    int t = threadIdx.x;                 // 512 = 8 waves
    int w = t >> 6, lane = t & 63;
    int i = b * NPER + t;
    float x = xq[i].x;
    float r = xsol[i] - x;
    float p = pred[i];
    float a1 = fabsf(r), a2 = fabsf(p);
    #pragma unroll
    for (int o = 32; o > 0; o >>= 1) {
        a1 += __shfl_down(a1, o, 64);
        a2 += __shfl_down(a2, o, 64);
    }
    if (lane == 0) { red[w] = a1; red2[w] = a2; }
    __syncthreads();
    float Sr = 1e-12f, Sp = 1e-12f;
    #pragma unroll
    for (int k = 0; k < 8; ++k) { Sr += red[k]; Sp += red2[k]; }
    out_labels[i * NSTEPS + step] = r / Sr;
    if (step == NSTEPS - 1) return;      // step-4 projection/update is dead work
    ddl[t] = p / Sp + 3.0f * tau / (x + tau);
    __syncthreads();

    // --- df[f] = sum_n P[b,n,f]*dd[n]: wave w rows w*64..+63, lane = 4 features
    float4 acc = {0.f, 0.f, 0.f, 0.f};
    size_t rowbase = (size_t)(b * NPER + w * 64) * FF;
    if (step == 0) {
        const float4* Pr = (const float4*)(Pf + rowbase) + lane;
        uint2* Pw = (uint2*)(Pbf + rowbase) + lane;
        #pragma unroll 4
        for (int n = 0; n < 64; ++n) {
            float4 pv = Pr[(size_t)n * 64];
            float sc = ddl[w * 64 + n];
            acc.x += pv.x * sc; acc.y += pv.y * sc;
            acc.z += pv.z * sc; acc.w += pv.w * sc;
            unsigned u0 = rtn_bf16(__float_as_uint(pv.x));
            unsigned u1 = rtn_bf16(__float_as_uint(pv.y));
            unsigned u2 = rtn_bf16(__float_as_uint(pv.z));
            unsigned u3 = rtn_bf16(__float_as_uint(pv.w));
            uint2 o; o.x = u0 | (u1 << 16); o.y = u2 | (u3 << 16);
            Pw[(size_t)n * 64] = o;
        }
    } else {
        const uint2* Pr = (const uint2*)(Pbf + rowbase) + lane;
        #pragma unroll 8
        for (int n = 0; n < 64; ++n) {
            uint2 pv = Pr[(size_t)n * 64];
            float sc = ddl[w * 64 + n];
            acc.x += bflo(pv.x) * sc; acc.y += bfhi(pv.x) * sc;
            acc.z += bflo(pv.y) * sc; acc.w += bfhi(pv.y) * sc;
        }
    }
    ((float4*)sl)[w * 64 + lane] = acc;
    __syncthreads();
    if (t < FF) {
        float v = 0.f;
        #pragma unroll
        for (int k = 0; k < 8; ++k) v += sl[k * FF + t];
        dfl[t] = v;
    }
    __syncthreads();

    // --- pproj[n] = P[b,n,:].df : 16 groups of 32 lanes, 32 rows each
    int g = t >> 5, l5 = t & 31;
    float4 dfa = ((const float4*)dfl)[l5 * 2];
    float4 dfb = ((const float4*)dfl)[l5 * 2 + 1];
    const uint4* Pr4 = (const uint4*)(Pbf + (size_t)(b * NPER + g * 32) * FF) + l5;
    #pragma unroll 4
    for (int it = 0; it < 32; ++it) {
        uint4 pv = Pr4[(size_t)it * 32];
        float a = bflo(pv.x) * dfa.x + bfhi(pv.x) * dfa.y
                + bflo(pv.y) * dfa.z + bfhi(pv.y) * dfa.w
                + bflo(pv.z) * dfb.x + bfhi(pv.z) * dfb.y
                + bflo(pv.w) * dfb.z + bfhi(pv.w) * dfb.w;
        #pragma unroll
        for (int o = 16; o > 0; o >>= 1) a += __shfl_down(a, o, 32);
        if (l5 == 0) pp[g * 32 + it] = a;
    }
    __syncthreads();

    // --- line search + update (block-local, no atomics)
    float d = pp[t];
    float ratio = (d < 0.f) ? (x / fmaxf(-d, 1e-12f)) : 5.0f;
    float m = ratio;
    #pragma unroll
    for (int o = 32; o > 0; o >>= 1) m = fminf(m, __shfl_down(m, o, 64));
    if (lane == 0) red[w] = m;
    __syncthreads();
    float mm = red[0];
    #pragma unroll
    for (int k = 1; k < 8; ++k) mm = fminf(mm, red[k]);
    float alpha = fminf(fmaxf(mm, 0.f), 5.0f) * 0.995f;
    xq[i].x = x + alpha * d;
}

// ---------------- launch ----------------

extern "C" void kernel_launch(void* const* d_in, const int* in_sizes, int n_in,
                              void* d_out, int out_size, void* d_ws, size_t ws_size,
                              hipStream_t stream) {
    const float* x_start = (const float*)d_in[0];
    const float* x_sol   = (const float*)d_in[1];
    const float* q       = (const float*)d_in[2];
    const float* P       = (const float*)d_in[3];
    const float* Win     = (const float*)d_in[4];
    const float* bin     = (const float*)d_in[5];
    const float* Wmsg    = (const float*)d_in[6];
    const float* bmsg    = (const float*)d_in[7];
    const float* Wout    = (const float*)d_in[8];
    const float* bout    = (const float*)d_in[9];
    const int*   esrc    = (const int*)d_in[10];
    const int*   edst    = (const int*)d_in[11];
    // d_in[12] vals_batch unused: batch(i) == i >> 9 (equal-sized contiguous graphs)

    float* out_preds  = (float*)d_out;                // [N, 4] row-major
    float* out_labels = (float*)d_out + (size_t)NN * NSTEPS;

    float* w = (float*)d_ws;
    float2* xq  = (float2*)w; w += 2 * (size_t)NN;
    float* pred  = w; w += NN;
    unsigned* deg      = (unsigned*)w; w += NN;
    unsigned* rowstart = (unsigned*)w; w += NN;
    unsigned* cursor   = (unsigned*)w; w += NN;
    unsigned* bsum     = (unsigned*)w; w += NN / 256;   // 512
    unsigned* bbase    = (unsigned*)w; w += NN / 256;   // 512
    int* csr_src       = (int*)w;      w += EE;
    unsigned short* Pbf = (unsigned short*)w;           // 64 MB bf16 copy of P

    // --- one-time: CSR build + xq pack (bf16 P cast is fused into step-0 k_step)
    hipMemsetAsync(deg, 0, NN * sizeof(unsigned), stream);
    k_degpack<<<EE / 256, 256, 0, stream>>>(edst, deg, x_start, q, xq);
    k_bsum<<<NN / 256, 256, 0, stream>>>(deg, bsum);
    k_scanb<<<1, NN / 256, 0, stream>>>(bsum, bbase);
    k_offsets<<<NN / 256, 256, 0, stream>>>(deg, bbase, rowstart, cursor);
    k_fill<<<EE / 256, 256, 0, stream>>>(esrc, edst, cursor, csr_src);

    float tau = 0.1f;
    for (int step = 0; step < NSTEPS; ++step) {
        k_node_g<<<NN / 8, 256, 0, stream>>>(xq, Win, bin, rowstart, deg, csr_src,
                                             Wmsg, bmsg, Wout, bout, pred, out_preds, step);
        k_step<<<BB, 512, 0, stream>>>(P, Pbf, xq, x_sol, pred, out_labels, tau, step);
        tau = fmaxf(tau * 0.5f, 1e-5f);
    }
}